// Round 1
// baseline (1020.068 us; speedup 1.0000x reference)
//
#include <hip/hip_runtime.h>
#include <stdint.h>

// Problem constants
#define N_TOK 4096
#define DIM   1024
#define HFRAC 2048
#define HSW   4096
#define NEXP  8
#define NFRAC 4
#define TOPK  2
#define TOTAL_ROWS (N_TOK * TOPK)   // 8192, always exact
#define PAD_ROWS   (TOTAL_ROWS + 128)

typedef unsigned short u16;
typedef __bf16 bf16x8 __attribute__((ext_vector_type(8)));
typedef float  floatx4 __attribute__((ext_vector_type(4)));

struct alignas(8)  us4 { u16 v[4]; };

__device__ __forceinline__ u16 f32_to_bf16_raw(float f) {
    union { float f; uint32_t u; } v; v.f = f;
    uint32_t u = v.u;
    uint32_t r = 0x7FFFu + ((u >> 16) & 1u);   // round-to-nearest-even
    return (u16)((u + r) >> 16);
}
__device__ __forceinline__ float bf16_raw_to_f32(u16 h) {
    union { uint32_t u; float f; } v; v.u = ((uint32_t)h) << 16;
    return v.f;
}

// async global->LDS, 16B per lane. LDS dest must be linear in lane order
// (wave-uniform base + lane*16) -- so LDS tiles are plain row-major, no pad.
__device__ __forceinline__ void gload16(const void* g, void* l) {
    __builtin_amdgcn_global_load_lds(
        (const __attribute__((address_space(1))) void*)g,
        (__attribute__((address_space(3))) void*)l, 16, 0, 0);
}

// ---------------------------------------------------------------- router
__global__ __launch_bounds__(256) void router_kernel(
    const float* __restrict__ x, const float* __restrict__ rw,
    int* __restrict__ re, float* __restrict__ rc, int* __restrict__ counts) {
    const int token = blockIdx.x * 4 + (threadIdx.x >> 6);
    const int lane  = threadIdx.x & 63;
    const float* xr = x + (size_t)token * DIM;

    float acc[NEXP];
#pragma unroll
    for (int e = 0; e < NEXP; ++e) acc[e] = 0.0f;
#pragma unroll
    for (int i = 0; i < DIM / 64; ++i) {
        int k = lane + i * 64;
        float xv = xr[k];
#pragma unroll
        for (int e = 0; e < NEXP; ++e) acc[e] += xv * rw[e * DIM + k];
    }
#pragma unroll
    for (int e = 0; e < NEXP; ++e) {
#pragma unroll
        for (int off = 32; off > 0; off >>= 1) acc[e] += __shfl_down(acc[e], off);
    }
    if (lane == 0) {
        float mx = acc[0];
#pragma unroll
        for (int e = 1; e < NEXP; ++e) mx = fmaxf(mx, acc[e]);
        float w[NEXP]; float s = 0.0f;
#pragma unroll
        for (int e = 0; e < NEXP; ++e) { w[e] = expf(acc[e] - mx); s += w[e]; }
        float inv = 1.0f / s;
#pragma unroll
        for (int e = 0; e < NEXP; ++e) w[e] *= inv;
        int i1 = 0;
#pragma unroll
        for (int e = 1; e < NEXP; ++e) if (w[e] > w[i1]) i1 = e;
        int i2 = (i1 == 0) ? 1 : 0;
#pragma unroll
        for (int e = 0; e < NEXP; ++e) if (e != i1 && w[e] > w[i2]) i2 = e;
        float denom = fmaxf(w[i1] + w[i2], 1e-9f);
        re[token]         = i1; rc[token]         = w[i1] / denom;
        re[N_TOK + token] = i2; rc[N_TOK + token] = w[i2] / denom;
        atomicAdd(&counts[i1], 1);
        atomicAdd(&counts[i2], 1);
    }
}

__global__ void offsets_kernel(const int* __restrict__ counts,
                               int* __restrict__ offs) {
    if (threadIdx.x == 0 && blockIdx.x == 0) {
        int a = 0;
#pragma unroll
        for (int e = 0; e < NEXP; ++e) { offs[e] = a; a += counts[e]; }
    }
}

__global__ __launch_bounds__(256) void scatter_kernel(
    const int* __restrict__ re, const float* __restrict__ rc,
    const int* __restrict__ offs, int* __restrict__ cursor,
    int* __restrict__ rowtok, float* __restrict__ co) {
    int token = blockIdx.x * 256 + threadIdx.x;
#pragma unroll
    for (int slot = 0; slot < TOPK; ++slot) {
        int e = re[slot * N_TOK + token];
        int i = atomicAdd(&cursor[e], 1);
        int r = offs[e] + i;
        rowtok[r] = token | (slot << 16);
        co[r]     = rc[slot * N_TOK + token];
    }
}

// gather+norm: A_g[r] = (e<4) ? bf16(rmsnorm(x[token], frac_rms[e])) : bf16(x[token])
__global__ __launch_bounds__(256) void gather_norm_kernel(
    const float* __restrict__ x, const float* __restrict__ frac_rms,
    const int* __restrict__ rowtok, const int* __restrict__ offs,
    u16* __restrict__ Ag) {
    const int r   = blockIdx.x;
    const int tid = threadIdx.x;
    if (r >= TOTAL_ROWS) {                 // zero-fill pad rows
        us4 z = {0, 0, 0, 0};
        reinterpret_cast<us4*>(Ag + (size_t)r * DIM)[tid] = z;
        return;
    }
    int e = 0;
#pragma unroll
    for (int i = 1; i < NEXP; ++i) if (r >= offs[i]) e = i;
    const int token = rowtok[r] & 0xFFFF;
    float4 v = reinterpret_cast<const float4*>(x + (size_t)token * DIM)[tid];
    if (e < NFRAC) {
        float ss = v.x * v.x + v.y * v.y + v.z * v.z + v.w * v.w;
#pragma unroll
        for (int off = 32; off > 0; off >>= 1) ss += __shfl_down(ss, off);
        __shared__ float red[4];
        if ((tid & 63) == 0) red[tid >> 6] = ss;
        __syncthreads();
        float scale = rsqrtf((red[0] + red[1] + red[2] + red[3]) * (1.0f / DIM) + 1e-6f);
        float4 wv = reinterpret_cast<const float4*>(frac_rms + (size_t)e * DIM)[tid];
        v.x *= scale * wv.x; v.y *= scale * wv.y;
        v.z *= scale * wv.z; v.w *= scale * wv.w;
    }
    us4 o = { f32_to_bf16_raw(v.x), f32_to_bf16_raw(v.y),
              f32_to_bf16_raw(v.z), f32_to_bf16_raw(v.w) };
    reinterpret_cast<us4*>(Ag + (size_t)r * DIM)[tid] = o;
}

// ------------------------------------------------- weight fp32->bf16 convert
// one launch per weight type; a = fractal part, b = switch part, concatenated.
#define FA4 (NFRAC * HFRAC * DIM / 4)          // 2,097,152 float4
#define SA4 ((NEXP - NFRAC) * HSW * DIM / 4)   // 4,194,304 float4
#define CVT_BLOCKS ((FA4 + SA4) / 256)         // 24576

__global__ __launch_bounds__(256) void cvt_pair_kernel(
    const float* __restrict__ a, const float* __restrict__ b,
    u16* __restrict__ dst) {
    size_t i = (size_t)blockIdx.x * 256 + threadIdx.x;
    const float4* src; size_t off;
    if (i < (size_t)FA4) { src = (const float4*)a; off = i; }
    else                 { src = (const float4*)b; off = i - FA4; }
    float4 v = src[off];
    us4 o = { f32_to_bf16_raw(v.x), f32_to_bf16_raw(v.y),
              f32_to_bf16_raw(v.z), f32_to_bf16_raw(v.w) };
    reinterpret_cast<us4*>(dst)[i] = o;
}

// ---------------------------------------------------------------- GEMM params
// m97 structure: 128x128 tile, BK=64, global_load_lds staging, linear LDS,
// 2-barrier K-loop. 4 waves in 2x2, each owns a 64x64 sub-tile (acc[4][4]).
#define BM 128
#define BN 128
#define BK 64

// fused gemm1 (all experts): g = bf16(silu(A@W1^T) * (A@W3^T)) into gbuf
__global__ __launch_bounds__(256) void gemm1_kernel(
    const u16* __restrict__ Ag, const u16* __restrict__ W1b,
    const u16* __restrict__ W3b, u16* __restrict__ gbuf,
    const int* __restrict__ counts, const int* __restrict__ offs) {
    const int e   = blockIdx.z;
    const int cnt = counts[e];
    const int m0  = blockIdx.y * BM;
    if (m0 >= cnt) return;
    const int Ne = (e < NFRAC) ? HFRAC : HSW;
    const int n0 = blockIdx.x * BN;
    if (n0 >= Ne) return;
    const int rowbase = offs[e];
    const size_t wofs = (e < NFRAC)
        ? (size_t)e * HFRAC * DIM
        : (size_t)NFRAC * HFRAC * DIM + (size_t)(e - NFRAC) * HSW * DIM;
    const u16* W1 = W1b + wofs + (size_t)n0 * DIM;
    const u16* W3 = W3b + wofs + (size_t)n0 * DIM;
    const u16* A  = Ag + (size_t)(rowbase + m0) * DIM;

    __shared__ u16 sA[BM * BK];    // 16 KB each, linear row-major [r][64]
    __shared__ u16 sB1[BN * BK];
    __shared__ u16 sB3[BN * BK];

    const int tid  = threadIdx.x;
    const int lane = tid & 63;
    const int wave = tid >> 6;
    const int wr   = wave >> 1, wc = wave & 1;
    const int rlo  = lane & 15, khi = lane >> 4;

    floatx4 acc1[4][4], acc3[4][4];
    floatx4 zero = { 0.f, 0.f, 0.f, 0.f };
#pragma unroll
    for (int mt = 0; mt < 4; ++mt)
#pragma unroll
        for (int nt = 0; nt < 4; ++nt) { acc1[mt][nt] = zero; acc3[mt][nt] = zero; }

    for (int k0 = 0; k0 < DIM; k0 += BK) {
#pragma unroll
        for (int it = 0; it < 4; ++it) {       // 1024 chunks of 16B per tile
            int ci = it * 256 + tid;
            int r = ci >> 3, c = (ci & 7) * 8;
            gload16(A  + (size_t)r * DIM + k0 + c, &sA [ci * 8]);
            gload16(W1 + (size_t)r * DIM + k0 + c, &sB1[ci * 8]);
            gload16(W3 + (size_t)r * DIM + k0 + c, &sB3[ci * 8]);
        }
        __syncthreads();
#pragma unroll
        for (int ks = 0; ks < 2; ++ks) {
            const int co = (ks * 4 + khi) * 8;
            bf16x8 af[4], b1[4], b3[4];
#pragma unroll
            for (int t = 0; t < 4; ++t) {
                af[t] = *reinterpret_cast<const bf16x8*>(&sA [(wr * 64 + t * 16 + rlo) * BK + co]);
                b1[t] = *reinterpret_cast<const bf16x8*>(&sB1[(wc * 64 + t * 16 + rlo) * BK + co]);
                b3[t] = *reinterpret_cast<const bf16x8*>(&sB3[(wc * 64 + t * 16 + rlo) * BK + co]);
            }
#pragma unroll
            for (int mt = 0; mt < 4; ++mt)
#pragma unroll
                for (int nt = 0; nt < 4; ++nt) {
                    acc1[mt][nt] = __builtin_amdgcn_mfma_f32_16x16x32_bf16(
                        af[mt], b1[nt], acc1[mt][nt], 0, 0, 0);
                    acc3[mt][nt] = __builtin_amdgcn_mfma_f32_16x16x32_bf16(
                        af[mt], b3[nt], acc3[mt][nt], 0, 0, 0);
                }
        }
        __syncthreads();
    }
#pragma unroll
    for (int mt = 0; mt < 4; ++mt)
#pragma unroll
        for (int nt = 0; nt < 4; ++nt)
#pragma unroll
            for (int r = 0; r < 4; ++r) {
                int row_local = m0 + wr * 64 + mt * 16 + khi * 4 + r;
                if (row_local >= cnt) continue;
                int col = n0 + wc * 64 + nt * 16 + rlo;
                float h1 = acc1[mt][nt][r];
                float h3 = acc3[mt][nt][r];
                float g = (h1 / (1.0f + expf(-h1))) * h3;
                gbuf[(size_t)(rowbase + row_local) * HSW + col] = f32_to_bf16_raw(g);
            }
}

// gemm2 (all experts): y = g @ W2^T, fused epilogue into ybuf[slot][token]
__global__ __launch_bounds__(256) void gemm2_kernel(
    const u16* __restrict__ gbuf, const u16* __restrict__ W2b,
    const u16* __restrict__ Ag, const float* __restrict__ x,
    const float* __restrict__ frac_gamma,
    const int* __restrict__ rowtok, const float* __restrict__ co,
    const int* __restrict__ counts, const int* __restrict__ offs,
    float* __restrict__ ybuf) {
    const int e   = blockIdx.z;
    const int cnt = counts[e];
    const int m0  = blockIdx.y * BM;
    if (m0 >= cnt) return;
    const int n0 = blockIdx.x * BN;       // over DIM, 8 tiles
    const int Ke = (e < NFRAC) ? HFRAC : HSW;
    const int rowbase = offs[e];
    const size_t wofs = (e < NFRAC)
        ? (size_t)e * DIM * HFRAC
        : (size_t)NFRAC * DIM * HFRAC + (size_t)(e - NFRAC) * DIM * HSW;
    const u16* W2 = W2b + wofs + (size_t)n0 * Ke;
    const u16* A  = gbuf + (size_t)(rowbase + m0) * HSW;

    __shared__ u16 sA[BM * BK];
    __shared__ u16 sB[BN * BK];

    const int tid  = threadIdx.x;
    const int lane = tid & 63;
    const int wave = tid >> 6;
    const int wr   = wave >> 1, wc = wave & 1;
    const int rlo  = lane & 15, khi = lane >> 4;

    floatx4 acc[4][4];
    floatx4 zero = { 0.f, 0.f, 0.f, 0.f };
#pragma unroll
    for (int mt = 0; mt < 4; ++mt)
#pragma unroll
        for (int nt = 0; nt < 4; ++nt) acc[mt][nt] = zero;

    for (int k0 = 0; k0 < Ke; k0 += BK) {
#pragma unroll
        for (int it = 0; it < 4; ++it) {
            int ci = it * 256 + tid;
            int r = ci >> 3, c = (ci & 7) * 8;
            gload16(A  + (size_t)r * HSW + k0 + c, &sA[ci * 8]);
            gload16(W2 + (size_t)r * Ke  + k0 + c, &sB[ci * 8]);
        }
        __syncthreads();
#pragma unroll
        for (int ks = 0; ks < 2; ++ks) {
            const int co = (ks * 4 + khi) * 8;
            bf16x8 af[4], bf[4];
#pragma unroll
            for (int t = 0; t < 4; ++t) {
                af[t] = *reinterpret_cast<const bf16x8*>(&sA[(wr * 64 + t * 16 + rlo) * BK + co]);
                bf[t] = *reinterpret_cast<const bf16x8*>(&sB[(wc * 64 + t * 16 + rlo) * BK + co]);
            }
#pragma unroll
            for (int mt = 0; mt < 4; ++mt)
#pragma unroll
                for (int nt = 0; nt < 4; ++nt)
                    acc[mt][nt] = __builtin_amdgcn_mfma_f32_16x16x32_bf16(
                        af[mt], bf[nt], acc[mt][nt], 0, 0, 0);
        }
        __syncthreads();
    }
    const float* gamma = frac_gamma + (size_t)e * DIM;
#pragma unroll
    for (int mt = 0; mt < 4; ++mt)
#pragma unroll
        for (int nt = 0; nt < 4; ++nt)
#pragma unroll
            for (int rr = 0; rr < 4; ++rr) {
                int row_local = m0 + wr * 64 + mt * 16 + khi * 4 + rr;
                if (row_local >= cnt) continue;
                int r = rowbase + row_local;
                int col = n0 + wc * 64 + nt * 16 + rlo;
                int info  = rowtok[r];
                int token = info & 0xFFFF;
                int slot  = info >> 16;
                float coef = co[r];
                float y = acc[mt][nt][rr];
                float val;
                if (e < NFRAC) {
                    float xn = bf16_raw_to_f32(Ag[(size_t)r * DIM + col]);
                    val = coef * (gamma[col] * (xn + y) + x[(size_t)token * DIM + col]);
                } else {
                    val = coef * y;
                }
                ybuf[(size_t)slot * N_TOK * DIM + (size_t)token * DIM + col] = val;
            }
}

// out = ybuf[0] + ybuf[1]
__global__ __launch_bounds__(256) void combine_kernel(
    const float* __restrict__ ybuf, float* __restrict__ out) {
    size_t i = (size_t)blockIdx.x * 256 + threadIdx.x;   // float4 index
    float4 a = reinterpret_cast<const float4*>(ybuf)[i];
    float4 b = reinterpret_cast<const float4*>(ybuf + (size_t)N_TOK * DIM)[i];
    float4 o = { a.x + b.x, a.y + b.y, a.z + b.z, a.w + b.w };
    reinterpret_cast<float4*>(out)[i] = o;
}

// ---------------------------------------------------------------- launch
extern "C" void kernel_launch(void* const* d_in, const int* in_sizes, int n_in,
                              void* d_out, int out_size, void* d_ws, size_t ws_size,
                              hipStream_t stream) {
    const float* x          = (const float*)d_in[0];
    const float* router_w   = (const float*)d_in[1];
    const float* frac_rms   = (const float*)d_in[2];
    const float* frac_w1    = (const float*)d_in[3];
    const float* frac_w2    = (const float*)d_in[4];
    const float* frac_w3    = (const float*)d_in[5];
    const float* frac_gamma = (const float*)d_in[6];
    const float* sw_w1      = (const float*)d_in[7];
    const float* sw_w2      = (const float*)d_in[8];
    const float* sw_w3      = (const float*)d_in[9];
    float* out = (float*)d_out;

    // workspace layout (peak 180 MiB):
    //   [0,256K)       control + routing arrays
    //   [256K,~16.8M)  Ag      (PAD_ROWS*DIM bf16,   17.0 MB)
    //   [18M,~83M)     gbuf    (PAD_ROWS*HSW bf16,   68.2 MB)
    //   [84M,132M)     W1b     (48 MiB bf16)  } live: cvt -> gemm1
    //   [132M,180M)    W3b     (48 MiB bf16)  }
    //   [84M,132M)     W2b     overlaps dead W1b, live: cvt2 -> gemm2
    //   [132M,164M)    ybuf    overlaps dead W3b, live: gemm2 -> combine
    char* ws = (char*)d_ws;
    int*   counts = (int*)ws;                          // 8 ints
    int*   cursor = (int*)(ws + 32);                   // 8 ints
    int*   offs   = (int*)(ws + 64);                   // 8 ints
    int*   re     = (int*)(ws + 256);                  // 32 KB
    float* rc     = (float*)(ws + 256 + (32u << 10));  // 32 KB
    int*   rowtok = (int*)(ws + 256 + (64u << 10));    // ~33 KB
    float* co     = (float*)(ws + 256 + (112u << 10)); // ~33 KB
    u16*   Ag     = (u16*)(ws + (1u << 18));
    u16*   gbuf   = (u16*)(ws + (size_t)18  * (1u << 20));
    u16*   W1b    = (u16*)(ws + (size_t)84  * (1u << 20));
    u16*   W3b    = (u16*)(ws + (size_t)132 * (1u << 20));
    u16*   W2b    = (u16*)(ws + (size_t)84  * (1u << 20));   // overlap W1b
    float* ybuf   = (float*)(ws + (size_t)132 * (1u << 20)); // overlap W3b

    hipMemsetAsync(ws, 0, 256, stream);  // counts + cursor

    // bf16 weight conversion for gemm1 operands (memory-bound, ~55 us)
    cvt_pair_kernel<<<CVT_BLOCKS, 256, 0, stream>>>(frac_w1, sw_w1, W1b);
    cvt_pair_kernel<<<CVT_BLOCKS, 256, 0, stream>>>(frac_w3, sw_w3, W3b);

    router_kernel<<<N_TOK / 4, 256, 0, stream>>>(x, router_w, re, rc, counts);
    offsets_kernel<<<1, 64, 0, stream>>>(counts, offs);
    scatter_kernel<<<N_TOK / 256, 256, 0, stream>>>(re, rc, offs, cursor, rowtok, co);
    gather_norm_kernel<<<PAD_ROWS, 256, 0, stream>>>(x, frac_rms, rowtok, offs, Ag);

    gemm1_kernel<<<dim3(HSW / BN, TOTAL_ROWS / BM, NEXP), 256, 0, stream>>>(
        Ag, W1b, W3b, gbuf, counts, offs);

    // W2 -> bf16 AFTER gemm1 (W2b overlaps W1b region)
    cvt_pair_kernel<<<CVT_BLOCKS, 256, 0, stream>>>(frac_w2, sw_w2, W2b);

    gemm2_kernel<<<dim3(DIM / BN, TOTAL_ROWS / BM, NEXP), 256, 0, stream>>>(
        gbuf, W2b, Ag, x, frac_gamma, rowtok, co, counts, offs, ybuf);

    combine_kernel<<<(N_TOK * DIM) / (4 * 256), 256, 0, stream>>>(ybuf, out);
}

// Round 2
// 971.089 us; speedup vs baseline: 1.0504x; 1.0504x over previous
//
#include <hip/hip_runtime.h>
#include <stdint.h>

// Problem constants
#define N_TOK 4096
#define DIM   1024
#define HFRAC 2048
#define HSW   4096
#define NEXP  8
#define NFRAC 4
#define TOPK  2
#define TOTAL_ROWS (N_TOK * TOPK)   // 8192, always exact
#define PAD_ROWS   (TOTAL_ROWS + 128)

typedef unsigned short u16;
typedef __bf16 bf16x8 __attribute__((ext_vector_type(8)));
typedef float  floatx4 __attribute__((ext_vector_type(4)));

struct alignas(8)  us4 { u16 v[4]; };

__device__ __forceinline__ u16 f32_to_bf16_raw(float f) {
    union { float f; uint32_t u; } v; v.f = f;
    uint32_t u = v.u;
    uint32_t r = 0x7FFFu + ((u >> 16) & 1u);   // round-to-nearest-even
    return (u16)((u + r) >> 16);
}
__device__ __forceinline__ float bf16_raw_to_f32(u16 h) {
    union { uint32_t u; float f; } v; v.u = ((uint32_t)h) << 16;
    return v.f;
}

// async global->LDS, 16B per lane. LDS dest must be linear in lane order
// (wave-uniform base + lane*16). Swizzle therefore lives on the GLOBAL
// source address at stage time + the LDS read address (rule #21 both-sides).
__device__ __forceinline__ void gload16(const void* g, void* l) {
    __builtin_amdgcn_global_load_lds(
        (const __attribute__((address_space(1))) void*)g,
        (__attribute__((address_space(3))) void*)l, 16, 0, 0);
}

// XOR-swizzled LDS element offset for 64-elem (128 B) rows in 16 B chunks:
// chunk' = chunk ^ (row&7). Involution; spreads a 16-row column-slice read
// across all 8 chunk positions -> 2 lanes/bank = conflict-free (m136).
__device__ __forceinline__ int sw_addr(int row, int chunk) {
    return row * 64 + ((chunk ^ (row & 7)) << 3);
}

// ---------------------------------------------------------------- router
__global__ __launch_bounds__(256) void router_kernel(
    const float* __restrict__ x, const float* __restrict__ rw,
    int* __restrict__ re, float* __restrict__ rc, int* __restrict__ counts) {
    const int token = blockIdx.x * 4 + (threadIdx.x >> 6);
    const int lane  = threadIdx.x & 63;
    const float* xr = x + (size_t)token * DIM;

    float acc[NEXP];
#pragma unroll
    for (int e = 0; e < NEXP; ++e) acc[e] = 0.0f;
#pragma unroll
    for (int i = 0; i < DIM / 64; ++i) {
        int k = lane + i * 64;
        float xv = xr[k];
#pragma unroll
        for (int e = 0; e < NEXP; ++e) acc[e] += xv * rw[e * DIM + k];
    }
#pragma unroll
    for (int e = 0; e < NEXP; ++e) {
#pragma unroll
        for (int off = 32; off > 0; off >>= 1) acc[e] += __shfl_down(acc[e], off);
    }
    if (lane == 0) {
        float mx = acc[0];
#pragma unroll
        for (int e = 1; e < NEXP; ++e) mx = fmaxf(mx, acc[e]);
        float w[NEXP]; float s = 0.0f;
#pragma unroll
        for (int e = 0; e < NEXP; ++e) { w[e] = expf(acc[e] - mx); s += w[e]; }
        float inv = 1.0f / s;
#pragma unroll
        for (int e = 0; e < NEXP; ++e) w[e] *= inv;
        int i1 = 0;
#pragma unroll
        for (int e = 1; e < NEXP; ++e) if (w[e] > w[i1]) i1 = e;
        int i2 = (i1 == 0) ? 1 : 0;
#pragma unroll
        for (int e = 0; e < NEXP; ++e) if (e != i1 && w[e] > w[i2]) i2 = e;
        float denom = fmaxf(w[i1] + w[i2], 1e-9f);
        re[token]         = i1; rc[token]         = w[i1] / denom;
        re[N_TOK + token] = i2; rc[N_TOK + token] = w[i2] / denom;
        atomicAdd(&counts[i1], 1);
        atomicAdd(&counts[i2], 1);
    }
}

__global__ void offsets_kernel(const int* __restrict__ counts,
                               int* __restrict__ offs) {
    if (threadIdx.x == 0 && blockIdx.x == 0) {
        int a = 0;
#pragma unroll
        for (int e = 0; e < NEXP; ++e) { offs[e] = a; a += counts[e]; }
    }
}

__global__ __launch_bounds__(256) void scatter_kernel(
    const int* __restrict__ re, const float* __restrict__ rc,
    const int* __restrict__ offs, int* __restrict__ cursor,
    int* __restrict__ rowtok, float* __restrict__ co) {
    int token = blockIdx.x * 256 + threadIdx.x;
#pragma unroll
    for (int slot = 0; slot < TOPK; ++slot) {
        int e = re[slot * N_TOK + token];
        int i = atomicAdd(&cursor[e], 1);
        int r = offs[e] + i;
        rowtok[r] = token | (slot << 16);
        co[r]     = rc[slot * N_TOK + token];
    }
}

// gather+norm: A_g[r] = (e<4) ? bf16(rmsnorm(x[token], frac_rms[e])) : bf16(x[token])
__global__ __launch_bounds__(256) void gather_norm_kernel(
    const float* __restrict__ x, const float* __restrict__ frac_rms,
    const int* __restrict__ rowtok, const int* __restrict__ offs,
    u16* __restrict__ Ag) {
    const int r   = blockIdx.x;
    const int tid = threadIdx.x;
    if (r >= TOTAL_ROWS) {                 // zero-fill pad rows
        us4 z = {0, 0, 0, 0};
        reinterpret_cast<us4*>(Ag + (size_t)r * DIM)[tid] = z;
        return;
    }
    int e = 0;
#pragma unroll
    for (int i = 1; i < NEXP; ++i) if (r >= offs[i]) e = i;
    const int token = rowtok[r] & 0xFFFF;
    float4 v = reinterpret_cast<const float4*>(x + (size_t)token * DIM)[tid];
    if (e < NFRAC) {
        float ss = v.x * v.x + v.y * v.y + v.z * v.z + v.w * v.w;
#pragma unroll
        for (int off = 32; off > 0; off >>= 1) ss += __shfl_down(ss, off);
        __shared__ float red[4];
        if ((tid & 63) == 0) red[tid >> 6] = ss;
        __syncthreads();
        float scale = rsqrtf((red[0] + red[1] + red[2] + red[3]) * (1.0f / DIM) + 1e-6f);
        float4 wv = reinterpret_cast<const float4*>(frac_rms + (size_t)e * DIM)[tid];
        v.x *= scale * wv.x; v.y *= scale * wv.y;
        v.z *= scale * wv.z; v.w *= scale * wv.w;
    }
    us4 o = { f32_to_bf16_raw(v.x), f32_to_bf16_raw(v.y),
              f32_to_bf16_raw(v.z), f32_to_bf16_raw(v.w) };
    reinterpret_cast<us4*>(Ag + (size_t)r * DIM)[tid] = o;
}

// ------------------------------------------------- weight fp32->bf16 convert
#define FA4 (NFRAC * HFRAC * DIM / 4)          // 2,097,152 float4
#define SA4 ((NEXP - NFRAC) * HSW * DIM / 4)   // 4,194,304 float4
#define CVT_BLOCKS ((FA4 + SA4) / 256)         // 24576

__global__ __launch_bounds__(256) void cvt_pair_kernel(
    const float* __restrict__ a, const float* __restrict__ b,
    u16* __restrict__ dst) {
    size_t i = (size_t)blockIdx.x * 256 + threadIdx.x;
    const float4* src; size_t off;
    if (i < (size_t)FA4) { src = (const float4*)a; off = i; }
    else                 { src = (const float4*)b; off = i - FA4; }
    float4 v = src[off];
    us4 o = { f32_to_bf16_raw(v.x), f32_to_bf16_raw(v.y),
              f32_to_bf16_raw(v.z), f32_to_bf16_raw(v.w) };
    reinterpret_cast<us4*>(dst)[i] = o;
}

// ---------------------------------------------------------------- GEMM params
// m97 structure: 128x128 tile, BK=64, global_load_lds staging with
// pre-swizzled global source + swizzled reads, 2-barrier K-loop.
// 4 waves in 2x2, each owns a 64x64 sub-tile (acc[4][4]).
#define BM 128
#define BN 128
#define BK 64

// fused gemm1 (all experts): g = bf16(silu(A@W1^T) * (A@W3^T)) into gbuf
__global__ __launch_bounds__(256) void gemm1_kernel(
    const u16* __restrict__ Ag, const u16* __restrict__ W1b,
    const u16* __restrict__ W3b, u16* __restrict__ gbuf,
    const int* __restrict__ counts, const int* __restrict__ offs) {
    const int e   = blockIdx.z;
    const int cnt = counts[e];
    const int m0  = blockIdx.y * BM;
    if (m0 >= cnt) return;
    const int Ne = (e < NFRAC) ? HFRAC : HSW;
    const int n0 = blockIdx.x * BN;
    if (n0 >= Ne) return;
    const int rowbase = offs[e];
    const size_t wofs = (e < NFRAC)
        ? (size_t)e * HFRAC * DIM
        : (size_t)NFRAC * HFRAC * DIM + (size_t)(e - NFRAC) * HSW * DIM;
    const u16* W1 = W1b + wofs + (size_t)n0 * DIM;
    const u16* W3 = W3b + wofs + (size_t)n0 * DIM;
    const u16* A  = Ag + (size_t)(rowbase + m0) * DIM;

    __shared__ u16 sA[BM * BK];    // 16 KB each; LDS is lane-linear,
    __shared__ u16 sB1[BN * BK];   // swizzle lives in the global src addr
    __shared__ u16 sB3[BN * BK];

    const int tid  = threadIdx.x;
    const int lane = tid & 63;
    const int wave = tid >> 6;
    const int wr   = wave >> 1, wc = wave & 1;
    const int rlo  = lane & 15, khi = lane >> 4;

    floatx4 acc1[4][4], acc3[4][4];
    floatx4 zero = { 0.f, 0.f, 0.f, 0.f };
#pragma unroll
    for (int mt = 0; mt < 4; ++mt)
#pragma unroll
        for (int nt = 0; nt < 4; ++nt) { acc1[mt][nt] = zero; acc3[mt][nt] = zero; }

    for (int k0 = 0; k0 < DIM; k0 += BK) {
#pragma unroll
        for (int it = 0; it < 4; ++it) {       // 1024 chunks of 16B per tile
            int ci = it * 256 + tid;
            int r = ci >> 3, cc = ci & 7;
            int csw = ((cc ^ (r & 7)) << 3);   // pre-swizzled source column
            gload16(A  + (size_t)r * DIM + k0 + csw, &sA [ci * 8]);
            gload16(W1 + (size_t)r * DIM + k0 + csw, &sB1[ci * 8]);
            gload16(W3 + (size_t)r * DIM + k0 + csw, &sB3[ci * 8]);
        }
        __syncthreads();
#pragma unroll
        for (int ks = 0; ks < 2; ++ks) {
            const int kk = ks * 4 + khi;       // chunk index 0..7
            bf16x8 af[4], b1[4], b3[4];
#pragma unroll
            for (int t = 0; t < 4; ++t) {
                af[t] = *reinterpret_cast<const bf16x8*>(&sA [sw_addr(wr * 64 + t * 16 + rlo, kk)]);
                b1[t] = *reinterpret_cast<const bf16x8*>(&sB1[sw_addr(wc * 64 + t * 16 + rlo, kk)]);
                b3[t] = *reinterpret_cast<const bf16x8*>(&sB3[sw_addr(wc * 64 + t * 16 + rlo, kk)]);
            }
#pragma unroll
            for (int mt = 0; mt < 4; ++mt)
#pragma unroll
                for (int nt = 0; nt < 4; ++nt) {
                    acc1[mt][nt] = __builtin_amdgcn_mfma_f32_16x16x32_bf16(
                        af[mt], b1[nt], acc1[mt][nt], 0, 0, 0);
                    acc3[mt][nt] = __builtin_amdgcn_mfma_f32_16x16x32_bf16(
                        af[mt], b3[nt], acc3[mt][nt], 0, 0, 0);
                }
        }
        __syncthreads();
    }
#pragma unroll
    for (int mt = 0; mt < 4; ++mt)
#pragma unroll
        for (int nt = 0; nt < 4; ++nt)
#pragma unroll
            for (int r = 0; r < 4; ++r) {
                int row_local = m0 + wr * 64 + mt * 16 + khi * 4 + r;
                if (row_local >= cnt) continue;
                int col = n0 + wc * 64 + nt * 16 + rlo;
                float h1 = acc1[mt][nt][r];
                float h3 = acc3[mt][nt][r];
                float g = (h1 / (1.0f + expf(-h1))) * h3;
                gbuf[(size_t)(rowbase + row_local) * HSW + col] = f32_to_bf16_raw(g);
            }
}

// gemm2 (all experts): y = g @ W2^T, fused epilogue into ybuf[slot][token]
__global__ __launch_bounds__(256) void gemm2_kernel(
    const u16* __restrict__ gbuf, const u16* __restrict__ W2b,
    const u16* __restrict__ Ag, const float* __restrict__ x,
    const float* __restrict__ frac_gamma,
    const int* __restrict__ rowtok, const float* __restrict__ co,
    const int* __restrict__ counts, const int* __restrict__ offs,
    float* __restrict__ ybuf) {
    const int e   = blockIdx.z;
    const int cnt = counts[e];
    const int m0  = blockIdx.y * BM;
    if (m0 >= cnt) return;
    const int n0 = blockIdx.x * BN;       // over DIM, 8 tiles
    const int Ke = (e < NFRAC) ? HFRAC : HSW;
    const int rowbase = offs[e];
    const size_t wofs = (e < NFRAC)
        ? (size_t)e * DIM * HFRAC
        : (size_t)NFRAC * DIM * HFRAC + (size_t)(e - NFRAC) * DIM * HSW;
    const u16* W2 = W2b + wofs + (size_t)n0 * Ke;
    const u16* A  = gbuf + (size_t)(rowbase + m0) * HSW;

    __shared__ u16 sA[BM * BK];
    __shared__ u16 sB[BN * BK];

    const int tid  = threadIdx.x;
    const int lane = tid & 63;
    const int wave = tid >> 6;
    const int wr   = wave >> 1, wc = wave & 1;
    const int rlo  = lane & 15, khi = lane >> 4;

    floatx4 acc[4][4];
    floatx4 zero = { 0.f, 0.f, 0.f, 0.f };
#pragma unroll
    for (int mt = 0; mt < 4; ++mt)
#pragma unroll
        for (int nt = 0; nt < 4; ++nt) acc[mt][nt] = zero;

    for (int k0 = 0; k0 < Ke; k0 += BK) {
#pragma unroll
        for (int it = 0; it < 4; ++it) {
            int ci = it * 256 + tid;
            int r = ci >> 3, cc = ci & 7;
            int csw = ((cc ^ (r & 7)) << 3);
            gload16(A  + (size_t)r * HSW + k0 + csw, &sA[ci * 8]);
            gload16(W2 + (size_t)r * Ke  + k0 + csw, &sB[ci * 8]);
        }
        __syncthreads();
#pragma unroll
        for (int ks = 0; ks < 2; ++ks) {
            const int kk = ks * 4 + khi;
            bf16x8 af[4], bf[4];
#pragma unroll
            for (int t = 0; t < 4; ++t) {
                af[t] = *reinterpret_cast<const bf16x8*>(&sA[sw_addr(wr * 64 + t * 16 + rlo, kk)]);
                bf[t] = *reinterpret_cast<const bf16x8*>(&sB[sw_addr(wc * 64 + t * 16 + rlo, kk)]);
            }
#pragma unroll
            for (int mt = 0; mt < 4; ++mt)
#pragma unroll
                for (int nt = 0; nt < 4; ++nt)
                    acc[mt][nt] = __builtin_amdgcn_mfma_f32_16x16x32_bf16(
                        af[mt], bf[nt], acc[mt][nt], 0, 0, 0);
        }
        __syncthreads();
    }
    const float* gamma = frac_gamma + (size_t)e * DIM;
#pragma unroll
    for (int mt = 0; mt < 4; ++mt)
#pragma unroll
        for (int nt = 0; nt < 4; ++nt)
#pragma unroll
            for (int rr = 0; rr < 4; ++rr) {
                int row_local = m0 + wr * 64 + mt * 16 + khi * 4 + rr;
                if (row_local >= cnt) continue;
                int r = rowbase + row_local;
                int col = n0 + wc * 64 + nt * 16 + rlo;
                int info  = rowtok[r];
                int token = info & 0xFFFF;
                int slot  = info >> 16;
                float coef = co[r];
                float y = acc[mt][nt][rr];
                float val;
                if (e < NFRAC) {
                    float xn = bf16_raw_to_f32(Ag[(size_t)r * DIM + col]);
                    val = coef * (gamma[col] * (xn + y) + x[(size_t)token * DIM + col]);
                } else {
                    val = coef * y;
                }
                ybuf[(size_t)slot * N_TOK * DIM + (size_t)token * DIM + col] = val;
            }
}

// out = ybuf[0] + ybuf[1]
__global__ __launch_bounds__(256) void combine_kernel(
    const float* __restrict__ ybuf, float* __restrict__ out) {
    size_t i = (size_t)blockIdx.x * 256 + threadIdx.x;   // float4 index
    float4 a = reinterpret_cast<const float4*>(ybuf)[i];
    float4 b = reinterpret_cast<const float4*>(ybuf + (size_t)N_TOK * DIM)[i];
    float4 o = { a.x + b.x, a.y + b.y, a.z + b.z, a.w + b.w };
    reinterpret_cast<float4*>(out)[i] = o;
}

// ---------------------------------------------------------------- launch
extern "C" void kernel_launch(void* const* d_in, const int* in_sizes, int n_in,
                              void* d_out, int out_size, void* d_ws, size_t ws_size,
                              hipStream_t stream) {
    const float* x          = (const float*)d_in[0];
    const float* router_w   = (const float*)d_in[1];
    const float* frac_rms   = (const float*)d_in[2];
    const float* frac_w1    = (const float*)d_in[3];
    const float* frac_w2    = (const float*)d_in[4];
    const float* frac_w3    = (const float*)d_in[5];
    const float* frac_gamma = (const float*)d_in[6];
    const float* sw_w1      = (const float*)d_in[7];
    const float* sw_w2      = (const float*)d_in[8];
    const float* sw_w3      = (const float*)d_in[9];
    float* out = (float*)d_out;

    // workspace layout (peak 180 MiB):
    //   [0,256K)        control + routing arrays
    //   [256K,~16.8M)   Ag      (PAD_ROWS*DIM bf16,  16.3 MiB)
    //   [18M,83M)       gbuf    (PAD_ROWS*HSW bf16,  65 MiB)
    //   [84M,132M)      W1b     (48 MiB bf16)  } live: cvt -> gemm1
    //   [132M,180M)     W3b     (48 MiB bf16)  }
    //   [84M,132M)      W2b     overlaps dead W1b, live: cvt2 -> gemm2
    //   [132M,164M)     ybuf    overlaps dead W3b, live: gemm2 -> combine
    char* ws = (char*)d_ws;
    int*   counts = (int*)ws;                          // 8 ints
    int*   cursor = (int*)(ws + 32);                   // 8 ints
    int*   offs   = (int*)(ws + 64);                   // 8 ints
    int*   re     = (int*)(ws + 256);                  // 32 KB
    float* rc     = (float*)(ws + 256 + (32u << 10));  // 32 KB
    int*   rowtok = (int*)(ws + 256 + (64u << 10));    // ~33 KB
    float* co     = (float*)(ws + 256 + (112u << 10)); // ~33 KB
    u16*   Ag     = (u16*)(ws + (1u << 18));
    u16*   gbuf   = (u16*)(ws + (size_t)18  * (1u << 20));
    u16*   W1b    = (u16*)(ws + (size_t)84  * (1u << 20));
    u16*   W3b    = (u16*)(ws + (size_t)132 * (1u << 20));
    u16*   W2b    = (u16*)(ws + (size_t)84  * (1u << 20));   // overlap W1b
    float* ybuf   = (float*)(ws + (size_t)132 * (1u << 20)); // overlap W3b

    hipMemsetAsync(ws, 0, 256, stream);  // counts + cursor

    // bf16 weight conversion for gemm1 operands (memory-bound)
    cvt_pair_kernel<<<CVT_BLOCKS, 256, 0, stream>>>(frac_w1, sw_w1, W1b);
    cvt_pair_kernel<<<CVT_BLOCKS, 256, 0, stream>>>(frac_w3, sw_w3, W3b);

    router_kernel<<<N_TOK / 4, 256, 0, stream>>>(x, router_w, re, rc, counts);
    offsets_kernel<<<1, 64, 0, stream>>>(counts, offs);
    scatter_kernel<<<N_TOK / 256, 256, 0, stream>>>(re, rc, offs, cursor, rowtok, co);
    gather_norm_kernel<<<PAD_ROWS, 256, 0, stream>>>(x, frac_rms, rowtok, offs, Ag);

    gemm1_kernel<<<dim3(HSW / BN, TOTAL_ROWS / BM, NEXP), 256, 0, stream>>>(
        Ag, W1b, W3b, gbuf, counts, offs);

    // W2 -> bf16 AFTER gemm1 (W2b overlaps W1b region)
    cvt_pair_kernel<<<CVT_BLOCKS, 256, 0, stream>>>(frac_w2, sw_w2, W2b);

    gemm2_kernel<<<dim3(DIM / BN, TOTAL_ROWS / BM, NEXP), 256, 0, stream>>>(
        gbuf, W2b, Ag, x, frac_gamma, rowtok, co, counts, offs, ybuf);

    combine_kernel<<<(N_TOK * DIM) / (4 * 256), 256, 0, stream>>>(ybuf, out);
}

// Round 3
// 744.039 us; speedup vs baseline: 1.3710x; 1.3052x over previous
//
#include <hip/hip_runtime.h>
#include <stdint.h>

// Problem constants
#define N_TOK 4096
#define DIM   1024
#define HFRAC 2048
#define HSW   4096
#define NEXP  8
#define NFRAC 4
#define TOPK  2
#define TOTAL_ROWS (N_TOK * TOPK)   // 8192, always exact
#define PAD_ROWS   (TOTAL_ROWS + 128)

typedef unsigned short u16;
typedef __bf16 bf16x8 __attribute__((ext_vector_type(8)));
typedef float  floatx4 __attribute__((ext_vector_type(4)));

struct alignas(8)  us4 { u16 v[4]; };

__device__ __forceinline__ u16 f32_to_bf16_raw(float f) {
    union { float f; uint32_t u; } v; v.f = f;
    uint32_t u = v.u;
    uint32_t r = 0x7FFFu + ((u >> 16) & 1u);   // round-to-nearest-even
    return (u16)((u + r) >> 16);
}
__device__ __forceinline__ float bf16_raw_to_f32(u16 h) {
    union { uint32_t u; float f; } v; v.u = ((uint32_t)h) << 16;
    return v.f;
}

// async global->LDS, 16B per lane. LDS dest is lane-linear; the XOR swizzle
// lives on the GLOBAL source address at stage time + the LDS read address.
__device__ __forceinline__ void gload16(const void* g, void* l) {
    __builtin_amdgcn_global_load_lds(
        (const __attribute__((address_space(1))) void*)g,
        (__attribute__((address_space(3))) void*)l, 16, 0, 0);
}

// XOR-swizzled LDS element offset for 64-elem (128 B) rows in 16 B chunks:
// chunk' = chunk ^ (row&7). 16-row column-slice reads spread across all 8
// chunk slots -> 2 lanes/bank = free (m136).
__device__ __forceinline__ int sw_addr(int row, int chunk) {
    return row * 64 + ((chunk ^ (row & 7)) << 3);
}

// ---------------------------------------------------------------- router
__global__ __launch_bounds__(256) void router_kernel(
    const float* __restrict__ x, const float* __restrict__ rw,
    int* __restrict__ re, float* __restrict__ rc, int* __restrict__ counts) {
    const int token = blockIdx.x * 4 + (threadIdx.x >> 6);
    const int lane  = threadIdx.x & 63;
    const float* xr = x + (size_t)token * DIM;

    float acc[NEXP];
#pragma unroll
    for (int e = 0; e < NEXP; ++e) acc[e] = 0.0f;
#pragma unroll
    for (int i = 0; i < DIM / 64; ++i) {
        int k = lane + i * 64;
        float xv = xr[k];
#pragma unroll
        for (int e = 0; e < NEXP; ++e) acc[e] += xv * rw[e * DIM + k];
    }
#pragma unroll
    for (int e = 0; e < NEXP; ++e) {
#pragma unroll
        for (int off = 32; off > 0; off >>= 1) acc[e] += __shfl_down(acc[e], off);
    }
    if (lane == 0) {
        float mx = acc[0];
#pragma unroll
        for (int e = 1; e < NEXP; ++e) mx = fmaxf(mx, acc[e]);
        float w[NEXP]; float s = 0.0f;
#pragma unroll
        for (int e = 0; e < NEXP; ++e) { w[e] = expf(acc[e] - mx); s += w[e]; }
        float inv = 1.0f / s;
#pragma unroll
        for (int e = 0; e < NEXP; ++e) w[e] *= inv;
        int i1 = 0;
#pragma unroll
        for (int e = 1; e < NEXP; ++e) if (w[e] > w[i1]) i1 = e;
        int i2 = (i1 == 0) ? 1 : 0;
#pragma unroll
        for (int e = 0; e < NEXP; ++e) if (e != i1 && w[e] > w[i2]) i2 = e;
        float denom = fmaxf(w[i1] + w[i2], 1e-9f);
        re[token]         = i1; rc[token]         = w[i1] / denom;
        re[N_TOK + token] = i2; rc[N_TOK + token] = w[i2] / denom;
        atomicAdd(&counts[i1], 1);
        atomicAdd(&counts[i2], 1);
    }
}

__global__ void offsets_kernel(const int* __restrict__ counts,
                               int* __restrict__ offs) {
    if (threadIdx.x == 0 && blockIdx.x == 0) {
        int a = 0;
#pragma unroll
        for (int e = 0; e < NEXP; ++e) { offs[e] = a; a += counts[e]; }
    }
}

__global__ __launch_bounds__(256) void scatter_kernel(
    const int* __restrict__ re, const float* __restrict__ rc,
    const int* __restrict__ offs, int* __restrict__ cursor,
    int* __restrict__ rowtok, float* __restrict__ co) {
    int token = blockIdx.x * 256 + threadIdx.x;
#pragma unroll
    for (int slot = 0; slot < TOPK; ++slot) {
        int e = re[slot * N_TOK + token];
        int i = atomicAdd(&cursor[e], 1);
        int r = offs[e] + i;
        rowtok[r] = token | (slot << 16);
        co[r]     = rc[slot * N_TOK + token];
    }
}

// gather+norm: A_g[r] = (e<4) ? bf16(rmsnorm(x[token], frac_rms[e])) : bf16(x[token])
__global__ __launch_bounds__(256) void gather_norm_kernel(
    const float* __restrict__ x, const float* __restrict__ frac_rms,
    const int* __restrict__ rowtok, const int* __restrict__ offs,
    u16* __restrict__ Ag) {
    const int r   = blockIdx.x;
    const int tid = threadIdx.x;
    if (r >= TOTAL_ROWS) {                 // zero-fill pad rows
        us4 z = {0, 0, 0, 0};
        reinterpret_cast<us4*>(Ag + (size_t)r * DIM)[tid] = z;
        return;
    }
    int e = 0;
#pragma unroll
    for (int i = 1; i < NEXP; ++i) if (r >= offs[i]) e = i;
    const int token = rowtok[r] & 0xFFFF;
    float4 v = reinterpret_cast<const float4*>(x + (size_t)token * DIM)[tid];
    if (e < NFRAC) {
        float ss = v.x * v.x + v.y * v.y + v.z * v.z + v.w * v.w;
#pragma unroll
        for (int off = 32; off > 0; off >>= 1) ss += __shfl_down(ss, off);
        __shared__ float red[4];
        if ((tid & 63) == 0) red[tid >> 6] = ss;
        __syncthreads();
        float scale = rsqrtf((red[0] + red[1] + red[2] + red[3]) * (1.0f / DIM) + 1e-6f);
        float4 wv = reinterpret_cast<const float4*>(frac_rms + (size_t)e * DIM)[tid];
        v.x *= scale * wv.x; v.y *= scale * wv.y;
        v.z *= scale * wv.z; v.w *= scale * wv.w;
    }
    us4 o = { f32_to_bf16_raw(v.x), f32_to_bf16_raw(v.y),
              f32_to_bf16_raw(v.z), f32_to_bf16_raw(v.w) };
    reinterpret_cast<us4*>(Ag + (size_t)r * DIM)[tid] = o;
}

// ------------------------------------------------- weight fp32->bf16 convert
#define FA4 (NFRAC * HFRAC * DIM / 4)          // 2,097,152 float4
#define SA4 ((NEXP - NFRAC) * HSW * DIM / 4)   // 4,194,304 float4
#define CVT_BLOCKS ((FA4 + SA4) / 256)         // 24576

__global__ __launch_bounds__(256) void cvt_pair_kernel(
    const float* __restrict__ a, const float* __restrict__ b,
    u16* __restrict__ dst) {
    size_t i = (size_t)blockIdx.x * 256 + threadIdx.x;
    const float4* src; size_t off;
    if (i < (size_t)FA4) { src = (const float4*)a; off = i; }
    else                 { src = (const float4*)b; off = i - FA4; }
    float4 v = src[off];
    us4 o = { f32_to_bf16_raw(v.x), f32_to_bf16_raw(v.y),
              f32_to_bf16_raw(v.z), f32_to_bf16_raw(v.w) };
    reinterpret_cast<us4*>(dst)[i] = o;
}

// ---------------------------------------------------------------- GEMM params
// 128x64 tile, BK=64, gload_lds + XOR swizzle, 2-barrier K-loop.
// LDS small (24-32 KB) so 4-6 blocks/CU resident hide the vmcnt(0) drain.
// Grid ordered (n, expert, m) so real blocks form a dense dispatch prefix.
#define BM 128
#define BN 64
#define BK 64

// fused gemm1 (all experts): g = bf16(silu(A@W1^T) * (A@W3^T)) into gbuf
__global__ __launch_bounds__(256, 4) void gemm1_kernel(
    const u16* __restrict__ Ag, const u16* __restrict__ W1b,
    const u16* __restrict__ W3b, u16* __restrict__ gbuf,
    const int* __restrict__ counts, const int* __restrict__ offs) {
    const int e   = blockIdx.y;
    const int cnt = counts[e];
    const int m0  = blockIdx.z * BM;
    if (m0 >= cnt) return;
    const int Ne = (e < NFRAC) ? HFRAC : HSW;
    const int n0 = blockIdx.x * BN;
    if (n0 >= Ne) return;
    const int rowbase = offs[e];
    const size_t wofs = (e < NFRAC)
        ? (size_t)e * HFRAC * DIM
        : (size_t)NFRAC * HFRAC * DIM + (size_t)(e - NFRAC) * HSW * DIM;
    const u16* W1 = W1b + wofs + (size_t)n0 * DIM;
    const u16* W3 = W3b + wofs + (size_t)n0 * DIM;
    const u16* A  = Ag + (size_t)(rowbase + m0) * DIM;

    __shared__ u16 sA[BM * BK];    // 16 KB
    __shared__ u16 sB1[BN * BK];   // 8 KB
    __shared__ u16 sB3[BN * BK];   // 8 KB   -> 32 KB total

    const int tid  = threadIdx.x;
    const int lane = tid & 63;
    const int wave = tid >> 6;
    const int wr   = wave >> 1, wc = wave & 1;
    const int rlo  = lane & 15, khi = lane >> 4;

    floatx4 acc1[4][2], acc3[4][2];
    floatx4 zero = { 0.f, 0.f, 0.f, 0.f };
#pragma unroll
    for (int mt = 0; mt < 4; ++mt)
#pragma unroll
        for (int nt = 0; nt < 2; ++nt) { acc1[mt][nt] = zero; acc3[mt][nt] = zero; }

    for (int k0 = 0; k0 < DIM; k0 += BK) {
#pragma unroll
        for (int it = 0; it < 4; ++it) {       // A: 1024 chunks of 16B
            int ci = it * 256 + tid;
            int r = ci >> 3, cc = ci & 7;
            int csw = ((cc ^ (r & 7)) << 3);   // pre-swizzled source column
            gload16(A + (size_t)r * DIM + k0 + csw, &sA[ci * 8]);
        }
#pragma unroll
        for (int it = 0; it < 2; ++it) {       // B1,B3: 512 chunks each
            int ci = it * 256 + tid;
            int r = ci >> 3, cc = ci & 7;
            int csw = ((cc ^ (r & 7)) << 3);
            gload16(W1 + (size_t)r * DIM + k0 + csw, &sB1[ci * 8]);
            gload16(W3 + (size_t)r * DIM + k0 + csw, &sB3[ci * 8]);
        }
        __syncthreads();
#pragma unroll
        for (int ks = 0; ks < 2; ++ks) {
            const int kk = ks * 4 + khi;       // chunk index 0..7
            bf16x8 af[4], b1[2], b3[2];
#pragma unroll
            for (int t = 0; t < 4; ++t)
                af[t] = *reinterpret_cast<const bf16x8*>(&sA[sw_addr(wr * 64 + t * 16 + rlo, kk)]);
#pragma unroll
            for (int t = 0; t < 2; ++t) {
                b1[t] = *reinterpret_cast<const bf16x8*>(&sB1[sw_addr(wc * 32 + t * 16 + rlo, kk)]);
                b3[t] = *reinterpret_cast<const bf16x8*>(&sB3[sw_addr(wc * 32 + t * 16 + rlo, kk)]);
            }
#pragma unroll
            for (int mt = 0; mt < 4; ++mt)
#pragma unroll
                for (int nt = 0; nt < 2; ++nt) {
                    acc1[mt][nt] = __builtin_amdgcn_mfma_f32_16x16x32_bf16(
                        af[mt], b1[nt], acc1[mt][nt], 0, 0, 0);
                    acc3[mt][nt] = __builtin_amdgcn_mfma_f32_16x16x32_bf16(
                        af[mt], b3[nt], acc3[mt][nt], 0, 0, 0);
                }
        }
        __syncthreads();
    }
#pragma unroll
    for (int mt = 0; mt < 4; ++mt)
#pragma unroll
        for (int nt = 0; nt < 2; ++nt)
#pragma unroll
            for (int r = 0; r < 4; ++r) {
                int row_local = m0 + wr * 64 + mt * 16 + khi * 4 + r;
                if (row_local >= cnt) continue;
                int col = n0 + wc * 32 + nt * 16 + rlo;
                float h1 = acc1[mt][nt][r];
                float h3 = acc3[mt][nt][r];
                float g = (h1 / (1.0f + expf(-h1))) * h3;
                gbuf[(size_t)(rowbase + row_local) * HSW + col] = f32_to_bf16_raw(g);
            }
}

// gemm2 (all experts): y = g @ W2^T, epilogue atomicAdd into out
// (each token gets exactly 2 expert contributions; fp32 add is commutative
//  so the result is order-independent/deterministic)
__global__ __launch_bounds__(256, 6) void gemm2_kernel(
    const u16* __restrict__ gbuf, const u16* __restrict__ W2b,
    const u16* __restrict__ Ag, const float* __restrict__ x,
    const float* __restrict__ frac_gamma,
    const int* __restrict__ rowtok, const float* __restrict__ co,
    const int* __restrict__ counts, const int* __restrict__ offs,
    float* __restrict__ out) {
    const int e   = blockIdx.y;
    const int cnt = counts[e];
    const int m0  = blockIdx.z * BM;
    if (m0 >= cnt) return;
    const int n0 = blockIdx.x * BN;       // over DIM, 16 tiles
    const int Ke = (e < NFRAC) ? HFRAC : HSW;
    const int rowbase = offs[e];
    const size_t wofs = (e < NFRAC)
        ? (size_t)e * DIM * HFRAC
        : (size_t)NFRAC * DIM * HFRAC + (size_t)(e - NFRAC) * DIM * HSW;
    const u16* W2 = W2b + wofs + (size_t)n0 * Ke;
    const u16* A  = gbuf + (size_t)(rowbase + m0) * HSW;

    __shared__ u16 sA[BM * BK];   // 16 KB
    __shared__ u16 sB[BN * BK];   // 8 KB -> 24 KB total

    const int tid  = threadIdx.x;
    const int lane = tid & 63;
    const int wave = tid >> 6;
    const int wr   = wave >> 1, wc = wave & 1;
    const int rlo  = lane & 15, khi = lane >> 4;

    floatx4 acc[4][2];
    floatx4 zero = { 0.f, 0.f, 0.f, 0.f };
#pragma unroll
    for (int mt = 0; mt < 4; ++mt)
#pragma unroll
        for (int nt = 0; nt < 2; ++nt) acc[mt][nt] = zero;

    for (int k0 = 0; k0 < Ke; k0 += BK) {
#pragma unroll
        for (int it = 0; it < 4; ++it) {
            int ci = it * 256 + tid;
            int r = ci >> 3, cc = ci & 7;
            int csw = ((cc ^ (r & 7)) << 3);
            gload16(A + (size_t)r * HSW + k0 + csw, &sA[ci * 8]);
        }
#pragma unroll
        for (int it = 0; it < 2; ++it) {
            int ci = it * 256 + tid;
            int r = ci >> 3, cc = ci & 7;
            int csw = ((cc ^ (r & 7)) << 3);
            gload16(W2 + (size_t)r * Ke + k0 + csw, &sB[ci * 8]);
        }
        __syncthreads();
#pragma unroll
        for (int ks = 0; ks < 2; ++ks) {
            const int kk = ks * 4 + khi;
            bf16x8 af[4], bf[2];
#pragma unroll
            for (int t = 0; t < 4; ++t)
                af[t] = *reinterpret_cast<const bf16x8*>(&sA[sw_addr(wr * 64 + t * 16 + rlo, kk)]);
#pragma unroll
            for (int t = 0; t < 2; ++t)
                bf[t] = *reinterpret_cast<const bf16x8*>(&sB[sw_addr(wc * 32 + t * 16 + rlo, kk)]);
#pragma unroll
            for (int mt = 0; mt < 4; ++mt)
#pragma unroll
                for (int nt = 0; nt < 2; ++nt)
                    acc[mt][nt] = __builtin_amdgcn_mfma_f32_16x16x32_bf16(
                        af[mt], bf[nt], acc[mt][nt], 0, 0, 0);
        }
        __syncthreads();
    }
    const float* gamma = frac_gamma + (size_t)e * DIM;
#pragma unroll
    for (int mt = 0; mt < 4; ++mt)
#pragma unroll
        for (int nt = 0; nt < 2; ++nt)
#pragma unroll
            for (int rr = 0; rr < 4; ++rr) {
                int row_local = m0 + wr * 64 + mt * 16 + khi * 4 + rr;
                if (row_local >= cnt) continue;
                int r = rowbase + row_local;
                int col = n0 + wc * 32 + nt * 16 + rlo;
                int token = rowtok[r] & 0xFFFF;
                float coef = co[r];
                float y = acc[mt][nt][rr];
                float val;
                if (e < NFRAC) {
                    float xn = bf16_raw_to_f32(Ag[(size_t)r * DIM + col]);
                    val = coef * (gamma[col] * (xn + y) + x[(size_t)token * DIM + col]);
                } else {
                    val = coef * y;
                }
                atomicAdd(&out[(size_t)token * DIM + col], val);
            }
}

// ---------------------------------------------------------------- launch
extern "C" void kernel_launch(void* const* d_in, const int* in_sizes, int n_in,
                              void* d_out, int out_size, void* d_ws, size_t ws_size,
                              hipStream_t stream) {
    const float* x          = (const float*)d_in[0];
    const float* router_w   = (const float*)d_in[1];
    const float* frac_rms   = (const float*)d_in[2];
    const float* frac_w1    = (const float*)d_in[3];
    const float* frac_w2    = (const float*)d_in[4];
    const float* frac_w3    = (const float*)d_in[5];
    const float* frac_gamma = (const float*)d_in[6];
    const float* sw_w1      = (const float*)d_in[7];
    const float* sw_w2      = (const float*)d_in[8];
    const float* sw_w3      = (const float*)d_in[9];
    float* out = (float*)d_out;

    // workspace layout (peak 180 MiB):
    //   [0,256K)        control + routing arrays
    //   [256K,~16.8M)   Ag      (PAD_ROWS*DIM bf16,  16.3 MiB)
    //   [18M,83M)       gbuf    (PAD_ROWS*HSW bf16,  65 MiB)
    //   [84M,132M)      W1b     (48 MiB bf16)  } live: cvt -> gemm1
    //   [132M,180M)     W3b     (48 MiB bf16)  }
    //   [84M,132M)      W2b     overlaps dead W1b, live: cvt2 -> gemm2
    char* ws = (char*)d_ws;
    int*   counts = (int*)ws;                          // 8 ints
    int*   cursor = (int*)(ws + 32);                   // 8 ints
    int*   offs   = (int*)(ws + 64);                   // 8 ints
    int*   re     = (int*)(ws + 256);                  // 32 KB
    float* rc     = (float*)(ws + 256 + (32u << 10));  // 32 KB
    int*   rowtok = (int*)(ws + 256 + (64u << 10));    // ~33 KB
    float* co     = (float*)(ws + 256 + (112u << 10)); // ~33 KB
    u16*   Ag     = (u16*)(ws + (1u << 18));
    u16*   gbuf   = (u16*)(ws + (size_t)18  * (1u << 20));
    u16*   W1b    = (u16*)(ws + (size_t)84  * (1u << 20));
    u16*   W3b    = (u16*)(ws + (size_t)132 * (1u << 20));
    u16*   W2b    = (u16*)(ws + (size_t)84  * (1u << 20));   // overlap W1b

    hipMemsetAsync(ws, 0, 256, stream);                 // counts + cursor
    hipMemsetAsync(out, 0, (size_t)N_TOK * DIM * 4, stream);  // atomic target

    // bf16 weight conversion for gemm1 operands (memory-bound)
    cvt_pair_kernel<<<CVT_BLOCKS, 256, 0, stream>>>(frac_w1, sw_w1, W1b);
    cvt_pair_kernel<<<CVT_BLOCKS, 256, 0, stream>>>(frac_w3, sw_w3, W3b);

    router_kernel<<<N_TOK / 4, 256, 0, stream>>>(x, router_w, re, rc, counts);
    offsets_kernel<<<1, 64, 0, stream>>>(counts, offs);
    scatter_kernel<<<N_TOK / 256, 256, 0, stream>>>(re, rc, offs, cursor, rowtok, co);
    gather_norm_kernel<<<PAD_ROWS, 256, 0, stream>>>(x, frac_rms, rowtok, offs, Ag);

    // grid (n-tiles, expert, m-tiles): real blocks are a dense dispatch prefix
    gemm1_kernel<<<dim3(HSW / BN, NEXP, TOTAL_ROWS / BM), 256, 0, stream>>>(
        Ag, W1b, W3b, gbuf, counts, offs);

    // W2 -> bf16 AFTER gemm1 (W2b overlaps W1b region)
    cvt_pair_kernel<<<CVT_BLOCKS, 256, 0, stream>>>(frac_w2, sw_w2, W2b);

    gemm2_kernel<<<dim3(DIM / BN, NEXP, TOTAL_ROWS / BM), 256, 0, stream>>>(
        gbuf, W2b, Ag, x, frac_gamma, rowtok, co, counts, offs, out);
}